// Round 1
// baseline (1330.349 us; speedup 1.0000x reference)
//
#include <hip/hip_runtime.h>

// Problem constants
#define B_    16
#define C_    512
#define S_    1024      // H*W = 32*32
#define OQKV  1536      // 3*C
#define NGRP  32
#define CPG   16        // C / NGRP

// ---------------------------------------------------------------------------
// GroupNorm: one block per (batch, group). 16 ch x 1024 = 16384 floats/group.
// ---------------------------------------------------------------------------
__global__ __launch_bounds__(256)
void gn_kernel(const float* __restrict__ x, const float* __restrict__ w,
               const float* __restrict__ b, float* __restrict__ xn) {
    int bg = blockIdx.x;
    int batch = bg / NGRP, g = bg % NGRP;
    const float* xp = x  + ((size_t)batch * C_ + (size_t)g * CPG) * S_;
    float*       op = xn + ((size_t)batch * C_ + (size_t)g * CPG) * S_;
    int tid = threadIdx.x;

    float s = 0.f, ss = 0.f;
    for (int i = tid; i < CPG * S_; i += 256) {
        float v = xp[i];
        s += v; ss += v * v;
    }
    // wave64 reduce
    for (int off = 32; off > 0; off >>= 1) {
        s  += __shfl_down(s, off);
        ss += __shfl_down(ss, off);
    }
    __shared__ float red[2][4];
    int wid = tid >> 6, lane = tid & 63;
    if (lane == 0) { red[0][wid] = s; red[1][wid] = ss; }
    __syncthreads();
    if (tid == 0) {
        float a = 0.f, c = 0.f;
        for (int i = 0; i < 4; ++i) { a += red[0][i]; c += red[1][i]; }
        float mean = a / (float)(CPG * S_);
        float var  = c / (float)(CPG * S_) - mean * mean;
        red[0][0] = mean;
        red[1][0] = rsqrtf(var + 1e-5f);
    }
    __syncthreads();
    float mean = red[0][0], inv = red[1][0];
    for (int i = tid; i < CPG * S_; i += 256) {
        int ch = g * CPG + i / S_;
        op[i] = (xp[i] - mean) * inv * w[ch] + b[ch];
    }
}

// ---------------------------------------------------------------------------
// Generic batched tiled GEMM: Y[m][n] = alpha * sum_k A(.)B(.) + bias[m] (+resid)
//   AT: A stored [K][M] (lda = M-ish row stride), else [M][K]
//   BT: B stored [N][K], else [K][N]
// BM=BN=64, BK=16, 256 threads, 4x4 micro-tile per thread.
// All problem dims divide the tile sizes — no bounds checks.
// ---------------------------------------------------------------------------
template<bool AT, bool BT>
__global__ __launch_bounds__(256)
void gemm_kernel(const float* __restrict__ A, const float* __restrict__ Bm,
                 const float* __restrict__ bias, const float* __restrict__ resid,
                 float* __restrict__ Y,
                 int lda, int ldb, int ldy, int K,
                 size_t sA, size_t sB, size_t sY, size_t sR, float alpha) {
    A  += (size_t)blockIdx.z * sA;
    Bm += (size_t)blockIdx.z * sB;
    Y  += (size_t)blockIdx.z * sY;
    const float* rp = resid ? resid + (size_t)blockIdx.z * sR : nullptr;

    int m0 = blockIdx.y * 64, n0 = blockIdx.x * 64;
    __shared__ float As[16][65];
    __shared__ float Bs[16][65];
    int tid = threadIdx.x, tx = tid & 15, ty = tid >> 4;

    float acc[4][4] = {};

    for (int k0 = 0; k0 < K; k0 += 16) {
        __syncthreads();
#pragma unroll
        for (int t = 0; t < 4; ++t) {
            int lin = tid + 256 * t;
            if (AT) { int k = lin >> 6, m = lin & 63;
                      As[k][m] = A[(size_t)(k0 + k) * lda + m0 + m]; }
            else    { int m = lin >> 4, k = lin & 15;
                      As[k][m] = A[(size_t)(m0 + m) * lda + k0 + k]; }
            if (BT) { int n = lin >> 4, k = lin & 15;
                      Bs[k][n] = Bm[(size_t)(n0 + n) * ldb + k0 + k]; }
            else    { int k = lin >> 6, n = lin & 63;
                      Bs[k][n] = Bm[(size_t)(k0 + k) * ldb + n0 + n]; }
        }
        __syncthreads();
#pragma unroll
        for (int kk = 0; kk < 16; ++kk) {
            float a[4], bb[4];
#pragma unroll
            for (int i = 0; i < 4; ++i) a[i]  = As[kk][ty + 16 * i];
#pragma unroll
            for (int j = 0; j < 4; ++j) bb[j] = Bs[kk][tx + 16 * j];
#pragma unroll
            for (int i = 0; i < 4; ++i)
#pragma unroll
                for (int j = 0; j < 4; ++j)
                    acc[i][j] += a[i] * bb[j];
        }
    }

#pragma unroll
    for (int i = 0; i < 4; ++i) {
        int m = m0 + ty + 16 * i;
        float bv = bias ? bias[m] : 0.f;
#pragma unroll
        for (int j = 0; j < 4; ++j) {
            int n = n0 + tx + 16 * j;
            float v = acc[i][j] * alpha + bv;
            if (rp) v += rp[(size_t)m * ldy + n];
            Y[(size_t)m * ldy + n] = v;
        }
    }
}

// ---------------------------------------------------------------------------
// Softmax over each aligned 32-element chunk of the key axis (the reference's
// softmax over the LAST axis only, W=32). One element/thread; each 32-lane
// half-wave owns exactly one chunk (block base is 256-aligned).
// ---------------------------------------------------------------------------
__global__ __launch_bounds__(256)
void softmax32_kernel(float* __restrict__ attn) {
    size_t idx = (size_t)blockIdx.x * 256 + threadIdx.x;
    float v = attn[idx];
    float m = v;
#pragma unroll
    for (int off = 16; off > 0; off >>= 1)
        m = fmaxf(m, __shfl_xor(m, off));
    float e = __expf(v - m);
    float s = e;
#pragma unroll
    for (int off = 16; off > 0; off >>= 1)
        s += __shfl_xor(s, off);
    attn[idx] = e / s;
}

// ---------------------------------------------------------------------------
extern "C" void kernel_launch(void* const* d_in, const int* in_sizes, int n_in,
                              void* d_out, int out_size, void* d_ws, size_t ws_size,
                              hipStream_t stream) {
    const float* x     = (const float*)d_in[0];
    const float* gn_w  = (const float*)d_in[1];
    const float* gn_b  = (const float*)d_in[2];
    const float* qkv_w = (const float*)d_in[3];
    const float* qkv_b = (const float*)d_in[4];
    const float* pr_w  = (const float*)d_in[5];
    const float* pr_b  = (const float*)d_in[6];
    float* out = (float*)d_out;

    float* ws   = (float*)d_ws;
    float* xn   = ws;                                   // [B][C][S]   (reused as attn_out)
    float* qkv  = ws + (size_t)B_ * C_ * S_;            // [B][3C][S]
    float* attn = qkv + (size_t)B_ * OQKV * S_;         // [B][S][S]
    // total: 50331648 floats = 192 MiB

    // 1) GroupNorm -> xn
    gn_kernel<<<B_ * NGRP, 256, 0, stream>>>(x, gn_w, gn_b, xn);

    // 2) qkv = qkv_w @ xn + qkv_b     (M=1536, N=1024, K=512), A:[M][K], B:[K][N]
    {
        dim3 grid(S_ / 64, OQKV / 64, B_);
        gemm_kernel<false, false><<<grid, 256, 0, stream>>>(
            qkv_w, xn, qkv_b, nullptr, qkv,
            C_, S_, S_, C_,
            0, (size_t)C_ * S_, (size_t)OQKV * S_, 0, 1.0f);
    }

    const float* q = qkv;                         // rows [0,512)
    const float* k = qkv + (size_t)C_ * S_;       // rows [512,1024)
    const float* v = qkv + (size_t)2 * C_ * S_;   // rows [1024,1536)

    // 3) attn[q][key] = 0.125 * sum_c q[c][q] k[c][key]   (M=N=1024, K=512)
    //    A = q stored [K][M] -> AT; B = k stored [K][N]
    {
        dim3 grid(S_ / 64, S_ / 64, B_);
        gemm_kernel<true, false><<<grid, 256, 0, stream>>>(
            q, k, nullptr, nullptr, attn,
            S_, S_, S_, C_,
            (size_t)OQKV * S_, (size_t)OQKV * S_, (size_t)S_ * S_, 0, 0.125f);
    }

    // 4) softmax over each aligned 32-key chunk
    {
        size_t total = (size_t)B_ * S_ * S_;      // 16M elements
        softmax32_kernel<<<(unsigned)(total / 256), 256, 0, stream>>>(attn);
    }

    // 5) attn_out[c][q] = sum_key v[c][key] * attn[q][key]  (M=512, N=1024, K=1024)
    //    A = v [M][K]; B = attn stored [N][K] -> BT. Write into xn buffer.
    {
        dim3 grid(S_ / 64, C_ / 64, B_);
        gemm_kernel<false, true><<<grid, 256, 0, stream>>>(
            v, attn, nullptr, nullptr, xn,
            S_, S_, S_, S_,
            (size_t)OQKV * S_, (size_t)S_ * S_, (size_t)C_ * S_, 0, 1.0f);
    }

    // 6) out = x + pr_w @ attn_out + pr_b   (M=512, N=1024, K=512)
    {
        dim3 grid(S_ / 64, C_ / 64, B_);
        gemm_kernel<false, false><<<grid, 256, 0, stream>>>(
            pr_w, xn, pr_b, x, out,
            C_, S_, S_, C_,
            0, (size_t)C_ * S_, (size_t)C_ * S_, (size_t)C_ * S_, 1.0f);
    }
}

// Round 2
// 289.550 us; speedup vs baseline: 4.5945x; 4.5945x over previous
//
#include <hip/hip_runtime.h>
#include <hip/hip_bf16.h>

#define B_    16
#define C_    512
#define S_    1024      // H*W
#define NGRP  32
#define CPG   16

typedef __attribute__((ext_vector_type(8))) short  short8;
typedef __attribute__((ext_vector_type(4))) float  floatx4;

// ---------------------------------------------------------------------------
// GroupNorm pass 1: per-(batch,group) mean / rsqrt(var). 512 blocks.
// ---------------------------------------------------------------------------
__global__ __launch_bounds__(256)
void gn_stats_kernel(const float* __restrict__ x, float* __restrict__ stats) {
    int bg = blockIdx.x;
    const float4* xp = (const float4*)(x + (size_t)bg * CPG * S_);
    int tid = threadIdx.x;
    float s = 0.f, ss = 0.f;
    for (int i = tid; i < CPG * S_ / 4; i += 256) {
        float4 v = xp[i];
        s  += v.x + v.y + v.z + v.w;
        ss += v.x*v.x + v.y*v.y + v.z*v.z + v.w*v.w;
    }
    for (int off = 32; off > 0; off >>= 1) {
        s  += __shfl_down(s, off);
        ss += __shfl_down(ss, off);
    }
    __shared__ float red[2][4];
    int wid = tid >> 6, lane = tid & 63;
    if (lane == 0) { red[0][wid] = s; red[1][wid] = ss; }
    __syncthreads();
    if (tid == 0) {
        float a = 0.f, c = 0.f;
        for (int i = 0; i < 4; ++i) { a += red[0][i]; c += red[1][i]; }
        float mean = a / (float)(CPG * S_);
        float var  = c / (float)(CPG * S_) - mean * mean;
        stats[bg * 2]     = mean;
        stats[bg * 2 + 1] = rsqrtf(var + 1e-5f);
    }
}

// ---------------------------------------------------------------------------
// GroupNorm pass 2 + transpose: xnT[b][s][c] (bf16, c contiguous).
// Block: (s-tile 64) x (c-tile 64) x batch. LDS 64x65 fp32 tile.
// ---------------------------------------------------------------------------
__global__ __launch_bounds__(256)
void gn_norm_t_kernel(const float* __restrict__ x, const float* __restrict__ w,
                      const float* __restrict__ bias, const float* __restrict__ stats,
                      __hip_bfloat16* __restrict__ xnT) {
    __shared__ float T[64][65];
    int b = blockIdx.z, c0 = blockIdx.y * 64, s0 = blockIdx.x * 64;
    int tid = threadIdx.x;
#pragma unroll
    for (int r = 0; r < 16; ++r) {
        int idx = r * 256 + tid;
        int ci = idx >> 6, si = idx & 63;
        int c = c0 + ci;
        float mean = stats[(b * NGRP + (c >> 4)) * 2];
        float inv  = stats[(b * NGRP + (c >> 4)) * 2 + 1];
        float v = x[((size_t)b * C_ + c) * S_ + s0 + si];
        T[ci][si] = (v - mean) * inv * w[c] + bias[c];
    }
    __syncthreads();
#pragma unroll
    for (int r = 0; r < 16; ++r) {
        int idx = r * 256 + tid;
        int si = idx >> 6, ci = idx & 63;
        xnT[((size_t)b * S_ + s0 + si) * C_ + c0 + ci] = __float2bfloat16(T[ci][si]);
    }
}

// ---------------------------------------------------------------------------
// fp32 -> bf16 convert (weights)
// ---------------------------------------------------------------------------
__global__ __launch_bounds__(256)
void f2bf_kernel(const float* __restrict__ in, __hip_bfloat16* __restrict__ out, int n) {
    int i = blockIdx.x * 256 + threadIdx.x;
    if (i < n) out[i] = __float2bfloat16(in[i]);
}

// ---------------------------------------------------------------------------
// Softmax over each aligned 32-key chunk; fp32 in, bf16 out.
// ---------------------------------------------------------------------------
__global__ __launch_bounds__(256)
void softmax32_kernel(const float* __restrict__ attn, __hip_bfloat16* __restrict__ P) {
    size_t idx = (size_t)blockIdx.x * 256 + threadIdx.x;
    float v = attn[idx];
    float m = v;
#pragma unroll
    for (int off = 16; off > 0; off >>= 1)
        m = fmaxf(m, __shfl_xor(m, off));
    float e = __expf(v - m);
    float s = e;
#pragma unroll
    for (int off = 16; off > 0; off >>= 1)
        s += __shfl_xor(s, off);
    P[idx] = __float2bfloat16(e / s);
}

// ---------------------------------------------------------------------------
// Uniform NT bf16 MFMA GEMM: C[m][n] = alpha * sum_k A[m][k]*B[n][k] (+bias)(+resid)
// A: [M][K] K-innermost (lda), B: [N][K] K-innermost (ldb). 128x128x32 tile,
// 256 threads = 4 waves, each wave 64x64 via 4x4 frags of 16x16x32.
// BIAS_MODE: 0 none, 1 bias[m], 2 bias[n].
// ---------------------------------------------------------------------------
template<int BIAS_MODE, bool OUT_BF16, bool RESID>
__global__ __launch_bounds__(256)
void mfma_gemm(const unsigned short* __restrict__ A, const unsigned short* __restrict__ Bm,
               const float* __restrict__ bias, const float* __restrict__ resid,
               void* __restrict__ Yv,
               int lda, int ldb, int ldy, int K,
               size_t sA, size_t sB, size_t sY, size_t sR, float alpha)
{
    __shared__ unsigned short As[128 * 32];
    __shared__ unsigned short Bs[128 * 32];
    const unsigned short* Ab = A  + (size_t)blockIdx.z * sA;
    const unsigned short* Bb = Bm + (size_t)blockIdx.z * sB;
    const int tid = threadIdx.x, wave = tid >> 6, lane = tid & 63;
    const int m0 = blockIdx.y * 128, n0 = blockIdx.x * 128;
    const int wr = wave >> 1, wc = wave & 1, lr = lane & 15, kq = lane >> 4;
    const int row0 = tid >> 2, kc0 = (tid & 3) << 3;

    floatx4 acc[4][4] = {};

    for (int k0 = 0; k0 < K; k0 += 32) {
        __syncthreads();
#pragma unroll
        for (int r = 0; r < 2; ++r) {
            // li = r*256 + tid -> row = r*64 + row0, kcol = kc0; lds base wave-uniform
            const unsigned short* ga = Ab + (size_t)(m0 + r * 64 + row0) * lda + k0 + kc0;
            __builtin_amdgcn_global_load_lds(
                (const __attribute__((address_space(1))) void*)ga,
                (__attribute__((address_space(3))) void*)(As + (r * 256 + wave * 64) * 8),
                16, 0, 0);
            const unsigned short* gb = Bb + (size_t)(n0 + r * 64 + row0) * ldb + k0 + kc0;
            __builtin_amdgcn_global_load_lds(
                (const __attribute__((address_space(1))) void*)gb,
                (__attribute__((address_space(3))) void*)(Bs + (r * 256 + wave * 64) * 8),
                16, 0, 0);
        }
        __syncthreads();

        short8 af[4], bfr[4];
#pragma unroll
        for (int i = 0; i < 4; ++i)
            af[i] = *(const short8*)&As[(wr * 64 + i * 16 + lr) * 32 + kq * 8];
#pragma unroll
        for (int j = 0; j < 4; ++j)
            bfr[j] = *(const short8*)&Bs[(wc * 64 + j * 16 + lr) * 32 + kq * 8];
#pragma unroll
        for (int i = 0; i < 4; ++i)
#pragma unroll
            for (int j = 0; j < 4; ++j)
                acc[i][j] = __builtin_amdgcn_mfma_f32_16x16x32_bf16(af[i], bfr[j], acc[i][j], 0, 0, 0);
    }

    const size_t ybase = (size_t)blockIdx.z * sY;
    const size_t rbase = (size_t)blockIdx.z * sR;
#pragma unroll
    for (int i = 0; i < 4; ++i) {
#pragma unroll
        for (int r = 0; r < 4; ++r) {
            int m = m0 + wr * 64 + i * 16 + kq * 4 + r;   // C/D: row = (lane>>4)*4+reg
            float bm = (BIAS_MODE == 1) ? bias[m] : 0.f;
#pragma unroll
            for (int j = 0; j < 4; ++j) {
                int n = n0 + wc * 64 + j * 16 + lr;       // C/D: col = lane&15
                float vv = acc[i][j][r] * alpha + bm;
                if (BIAS_MODE == 2) vv += bias[n];
                if (RESID) vv += resid[rbase + (size_t)m * ldy + n];
                if (OUT_BF16)
                    ((__hip_bfloat16*)Yv)[ybase + (size_t)m * ldy + n] = __float2bfloat16(vv);
                else
                    ((float*)Yv)[ybase + (size_t)m * ldy + n] = vv;
            }
        }
    }
}

// ---------------------------------------------------------------------------
extern "C" void kernel_launch(void* const* d_in, const int* in_sizes, int n_in,
                              void* d_out, int out_size, void* d_ws, size_t ws_size,
                              hipStream_t stream) {
    const float* x     = (const float*)d_in[0];
    const float* gn_w  = (const float*)d_in[1];
    const float* gn_b  = (const float*)d_in[2];
    const float* qkv_w = (const float*)d_in[3];
    const float* qkv_b = (const float*)d_in[4];
    const float* pr_w  = (const float*)d_in[5];
    const float* pr_b  = (const float*)d_in[6];
    float* out = (float*)d_out;

    char* w = (char*)d_ws;
    float*          attn = (float*)w;                                  // 64 MiB
    __hip_bfloat16* xnT  = (__hip_bfloat16*)(w + (64u << 20));         // 16 MiB [b][s][c]
    __hip_bfloat16* qkT  = (__hip_bfloat16*)(w + (80u << 20));         // 32 MiB [b*s][1024] (q|k)
    __hip_bfloat16* vbuf = (__hip_bfloat16*)(w + (112u << 20));        // 16 MiB [b][c][s]
    __hip_bfloat16* P    = (__hip_bfloat16*)(w + (128u << 20));        // 32 MiB [b][sq][sk]
    __hip_bfloat16* aoT  = (__hip_bfloat16*)(w + (160u << 20));        // 16 MiB [b*s][c]
    __hip_bfloat16* wq   = (__hip_bfloat16*)(w + (176u << 20));        // 1.5 MiB
    __hip_bfloat16* wp   = (__hip_bfloat16*)(w + (178u << 20));        // 0.5 MiB
    float*          stats= (float*)(w + (179u << 20));                 // 4 KiB

    // 1) GroupNorm stats + transposed normalize
    gn_stats_kernel<<<B_ * NGRP, 256, 0, stream>>>(x, stats);
    gn_norm_t_kernel<<<dim3(S_ / 64, C_ / 64, B_), 256, 0, stream>>>(x, gn_w, gn_b, stats, xnT);

    // 2) weight converts
    f2bf_kernel<<<(1536 * 512) / 256, 256, 0, stream>>>(qkv_w, wq, 1536 * 512);
    f2bf_kernel<<<(512 * 512) / 256, 256, 0, stream>>>(pr_w, wp, 512 * 512);

    // 3) q,k GEMM: M = B*S = 16384, N = 1024 (q|k channels), K = 512
    //    qkT[(b,s)][o] = xnT[(b,s)][:] . wq[o][:] + qkv_b[o]
    mfma_gemm<2, true, false><<<dim3(1024 / 128, 16384 / 128, 1), 256, 0, stream>>>(
        (const unsigned short*)xnT, (const unsigned short*)wq, qkv_b, nullptr, qkT,
        512, 512, 1024, 512, 0, 0, 0, 0, 1.f);

    // 4) v GEMM (batched): M = 512 (c), N = 1024 (s), K = 512 -> v[b][c][s]
    mfma_gemm<1, true, false><<<dim3(1024 / 128, 512 / 128, B_), 256, 0, stream>>>(
        (const unsigned short*)wq + 1024 * 512, (const unsigned short*)xnT,
        qkv_b + 1024, nullptr, vbuf,
        512, 512, 1024, 512, 0, (size_t)S_ * C_, (size_t)512 * S_, 0, 1.f);

    // 5) scores (batched): M = N = 1024, K = 512; attn = 0.125 * q.k
    mfma_gemm<0, false, false><<<dim3(8, 8, B_), 256, 0, stream>>>(
        (const unsigned short*)qkT, (const unsigned short*)qkT + 512, nullptr, nullptr, attn,
        1024, 1024, 1024, 512, (size_t)S_ * 1024, (size_t)S_ * 1024, (size_t)S_ * S_, 0, 0.125f);

    // 6) softmax over aligned 32-key chunks, bf16 out
    softmax32_kernel<<<(B_ * S_ * S_) / 256, 256, 0, stream>>>(attn, P);

    // 7) PV (batched): M = 1024 (sq), N = 512 (c), K = 1024 -> aoT[(b,s)][c]
    mfma_gemm<0, true, false><<<dim3(512 / 128, 1024 / 128, B_), 256, 0, stream>>>(
        (const unsigned short*)P, (const unsigned short*)vbuf, nullptr, nullptr, aoT,
        1024, 1024, 512, 1024, (size_t)S_ * S_, (size_t)512 * S_, (size_t)S_ * 512, 0, 1.f);

    // 8) proj + residual (batched): M = 512 (c), N = 1024 (s), K = 512
    mfma_gemm<1, false, true><<<dim3(1024 / 128, 512 / 128, B_), 256, 0, stream>>>(
        (const unsigned short*)wp, (const unsigned short*)aoT, pr_b, x, out,
        512, 512, 1024, 512, 0, (size_t)S_ * 512, (size_t)C_ * S_, (size_t)C_ * S_, 1.f);
}

// Round 3
// 266.610 us; speedup vs baseline: 4.9899x; 1.0860x over previous
//
#include <hip/hip_runtime.h>
#include <hip/hip_bf16.h>

#define B_    16
#define C_    512
#define S_    1024      // H*W
#define NGRP  32
#define CPG   16

typedef __attribute__((ext_vector_type(8))) short  short8;
typedef __attribute__((ext_vector_type(4))) float  floatx4;

// ---------------------------------------------------------------------------
// GroupNorm pass 1: per-(batch,group) mean / rsqrt(var). 512 blocks.
// ---------------------------------------------------------------------------
__global__ __launch_bounds__(256)
void gn_stats_kernel(const float* __restrict__ x, float* __restrict__ stats) {
    int bg = blockIdx.x;
    const float4* xp = (const float4*)(x + (size_t)bg * CPG * S_);
    int tid = threadIdx.x;
    float s = 0.f, ss = 0.f;
    for (int i = tid; i < CPG * S_ / 4; i += 256) {
        float4 v = xp[i];
        s  += v.x + v.y + v.z + v.w;
        ss += v.x*v.x + v.y*v.y + v.z*v.z + v.w*v.w;
    }
    for (int off = 32; off > 0; off >>= 1) {
        s  += __shfl_down(s, off);
        ss += __shfl_down(ss, off);
    }
    __shared__ float red[2][4];
    int wid = tid >> 6, lane = tid & 63;
    if (lane == 0) { red[0][wid] = s; red[1][wid] = ss; }
    __syncthreads();
    if (tid == 0) {
        float a = 0.f, c = 0.f;
        for (int i = 0; i < 4; ++i) { a += red[0][i]; c += red[1][i]; }
        float mean = a / (float)(CPG * S_);
        float var  = c / (float)(CPG * S_) - mean * mean;
        stats[bg * 2]     = mean;
        stats[bg * 2 + 1] = rsqrtf(var + 1e-5f);
    }
}

// ---------------------------------------------------------------------------
// GroupNorm pass 2 + transpose: xnT[b][s][c] (bf16, c contiguous).
// ---------------------------------------------------------------------------
__global__ __launch_bounds__(256)
void gn_norm_t_kernel(const float* __restrict__ x, const float* __restrict__ w,
                      const float* __restrict__ bias, const float* __restrict__ stats,
                      __hip_bfloat16* __restrict__ xnT) {
    __shared__ float T[64][65];
    int b = blockIdx.z, c0 = blockIdx.y * 64, s0 = blockIdx.x * 64;
    int tid = threadIdx.x;
#pragma unroll
    for (int r = 0; r < 16; ++r) {
        int idx = r * 256 + tid;
        int ci = idx >> 6, si = idx & 63;
        int c = c0 + ci;
        float mean = stats[(b * NGRP + (c >> 4)) * 2];
        float inv  = stats[(b * NGRP + (c >> 4)) * 2 + 1];
        float v = x[((size_t)b * C_ + c) * S_ + s0 + si];
        T[ci][si] = (v - mean) * inv * w[c] + bias[c];
    }
    __syncthreads();
#pragma unroll
    for (int r = 0; r < 16; ++r) {
        int idx = r * 256 + tid;
        int si = idx >> 6, ci = idx & 63;
        xnT[((size_t)b * S_ + s0 + si) * C_ + c0 + ci] = __float2bfloat16(T[ci][si]);
    }
}

// ---------------------------------------------------------------------------
__global__ __launch_bounds__(256)
void f2bf_kernel(const float* __restrict__ in, __hip_bfloat16* __restrict__ out, int n) {
    int i = blockIdx.x * 256 + threadIdx.x;
    if (i < n) out[i] = __float2bfloat16(in[i]);
}

// ---------------------------------------------------------------------------
// Uniform NT bf16 MFMA GEMM: C[m][n] = alpha * sum_k A[m][k]*B[n][k] (+bias)(+resid)
// 128x128x32 tile, 256 threads = 4 waves, each wave 64x64 via 4x4 16x16x32 frags.
// BIAS_MODE: 0 none, 1 bias[m], 2 bias[n].
// ---------------------------------------------------------------------------
template<int BIAS_MODE, bool OUT_BF16, bool RESID>
__global__ __launch_bounds__(256)
void mfma_gemm(const unsigned short* __restrict__ A, const unsigned short* __restrict__ Bm,
               const float* __restrict__ bias, const float* __restrict__ resid,
               void* __restrict__ Yv,
               int lda, int ldb, int ldy, int K,
               size_t sA, size_t sB, size_t sY, size_t sR, float alpha)
{
    __shared__ unsigned short As[128 * 32];
    __shared__ unsigned short Bs[128 * 32];
    const unsigned short* Ab = A  + (size_t)blockIdx.z * sA;
    const unsigned short* Bb = Bm + (size_t)blockIdx.z * sB;
    const int tid = threadIdx.x, wave = tid >> 6, lane = tid & 63;
    const int m0 = blockIdx.y * 128, n0 = blockIdx.x * 128;
    const int wr = wave >> 1, wc = wave & 1, lr = lane & 15, kq = lane >> 4;
    const int row0 = tid >> 2, kc0 = (tid & 3) << 3;

    floatx4 acc[4][4] = {};

    for (int k0 = 0; k0 < K; k0 += 32) {
        __syncthreads();
#pragma unroll
        for (int r = 0; r < 2; ++r) {
            const unsigned short* ga = Ab + (size_t)(m0 + r * 64 + row0) * lda + k0 + kc0;
            __builtin_amdgcn_global_load_lds(
                (const __attribute__((address_space(1))) void*)ga,
                (__attribute__((address_space(3))) void*)(As + (r * 256 + wave * 64) * 8),
                16, 0, 0);
            const unsigned short* gb = Bb + (size_t)(n0 + r * 64 + row0) * ldb + k0 + kc0;
            __builtin_amdgcn_global_load_lds(
                (const __attribute__((address_space(1))) void*)gb,
                (__attribute__((address_space(3))) void*)(Bs + (r * 256 + wave * 64) * 8),
                16, 0, 0);
        }
        __syncthreads();

        short8 af[4], bfr[4];
#pragma unroll
        for (int i = 0; i < 4; ++i)
            af[i] = *(const short8*)&As[(wr * 64 + i * 16 + lr) * 32 + kq * 8];
#pragma unroll
        for (int j = 0; j < 4; ++j)
            bfr[j] = *(const short8*)&Bs[(wc * 64 + j * 16 + lr) * 32 + kq * 8];
#pragma unroll
        for (int i = 0; i < 4; ++i)
#pragma unroll
            for (int j = 0; j < 4; ++j)
                acc[i][j] = __builtin_amdgcn_mfma_f32_16x16x32_bf16(af[i], bfr[j], acc[i][j], 0, 0, 0);
    }

    const size_t ybase = (size_t)blockIdx.z * sY;
    const size_t rbase = (size_t)blockIdx.z * sR;
#pragma unroll
    for (int i = 0; i < 4; ++i) {
#pragma unroll
        for (int r = 0; r < 4; ++r) {
            int m = m0 + wr * 64 + i * 16 + kq * 4 + r;
            float bm = (BIAS_MODE == 1) ? bias[m] : 0.f;
#pragma unroll
            for (int j = 0; j < 4; ++j) {
                int n = n0 + wc * 64 + j * 16 + lr;
                float vv = acc[i][j][r] * alpha + bm;
                if (BIAS_MODE == 2) vv += bias[n];
                if (RESID) vv += resid[rbase + (size_t)m * ldy + n];
                if (OUT_BF16)
                    ((__hip_bfloat16*)Yv)[ybase + (size_t)m * ldy + n] = __float2bfloat16(vv);
                else
                    ((float*)Yv)[ybase + (size_t)m * ldy + n] = vv;
            }
        }
    }
}

// ---------------------------------------------------------------------------
// Scores GEMM with FUSED 32-key-chunk softmax epilogue.
// C[m][n] = 0.125 * sum_k q[m][k] * k[n][k]; then softmax over each aligned
// 32-key chunk of n; P (bf16) written directly. Within a wave, a chunk is
// register pair j={2h,2h+1} x 16 lanes (lane&15) -> fmaxf + 4 shfl_xor.
// ---------------------------------------------------------------------------
__global__ __launch_bounds__(256)
void scores_softmax_kernel(const unsigned short* __restrict__ A,
                           const unsigned short* __restrict__ Bm,
                           __hip_bfloat16* __restrict__ P,
                           int lda, int ldb, int K,
                           size_t sA, size_t sB, size_t sP)
{
    __shared__ unsigned short As[128 * 32];
    __shared__ unsigned short Bs[128 * 32];
    const unsigned short* Ab = A  + (size_t)blockIdx.z * sA;
    const unsigned short* Bb = Bm + (size_t)blockIdx.z * sB;
    const int tid = threadIdx.x, wave = tid >> 6, lane = tid & 63;
    const int m0 = blockIdx.y * 128, n0 = blockIdx.x * 128;
    const int wr = wave >> 1, wc = wave & 1, lr = lane & 15, kq = lane >> 4;
    const int row0 = tid >> 2, kc0 = (tid & 3) << 3;

    floatx4 acc[4][4] = {};

    for (int k0 = 0; k0 < K; k0 += 32) {
        __syncthreads();
#pragma unroll
        for (int r = 0; r < 2; ++r) {
            const unsigned short* ga = Ab + (size_t)(m0 + r * 64 + row0) * lda + k0 + kc0;
            __builtin_amdgcn_global_load_lds(
                (const __attribute__((address_space(1))) void*)ga,
                (__attribute__((address_space(3))) void*)(As + (r * 256 + wave * 64) * 8),
                16, 0, 0);
            const unsigned short* gb = Bb + (size_t)(n0 + r * 64 + row0) * ldb + k0 + kc0;
            __builtin_amdgcn_global_load_lds(
                (const __attribute__((address_space(1))) void*)gb,
                (__attribute__((address_space(3))) void*)(Bs + (r * 256 + wave * 64) * 8),
                16, 0, 0);
        }
        __syncthreads();

        short8 af[4], bfr[4];
#pragma unroll
        for (int i = 0; i < 4; ++i)
            af[i] = *(const short8*)&As[(wr * 64 + i * 16 + lr) * 32 + kq * 8];
#pragma unroll
        for (int j = 0; j < 4; ++j)
            bfr[j] = *(const short8*)&Bs[(wc * 64 + j * 16 + lr) * 32 + kq * 8];
#pragma unroll
        for (int i = 0; i < 4; ++i)
#pragma unroll
            for (int j = 0; j < 4; ++j)
                acc[i][j] = __builtin_amdgcn_mfma_f32_16x16x32_bf16(af[i], bfr[j], acc[i][j], 0, 0, 0);
    }

    const size_t pbase = (size_t)blockIdx.z * sP;
#pragma unroll
    for (int i = 0; i < 4; ++i) {
#pragma unroll
        for (int r = 0; r < 4; ++r) {
            int m = m0 + wr * 64 + i * 16 + kq * 4 + r;
            size_t rowb = pbase + (size_t)m * 1024 + n0 + wc * 64;
#pragma unroll
            for (int h = 0; h < 2; ++h) {
                float s0 = acc[i][2 * h][r]     * 0.125f;
                float s1 = acc[i][2 * h + 1][r] * 0.125f;
                float mx = fmaxf(s0, s1);
#pragma unroll
                for (int off = 8; off >= 1; off >>= 1)
                    mx = fmaxf(mx, __shfl_xor(mx, off));
                float e0 = __expf(s0 - mx), e1 = __expf(s1 - mx);
                float sm = e0 + e1;
#pragma unroll
                for (int off = 8; off >= 1; off >>= 1)
                    sm += __shfl_xor(sm, off);
                float inv = 1.f / sm;
                P[rowb + 2 * h * 16 + lr]       = __float2bfloat16(e0 * inv);
                P[rowb + (2 * h + 1) * 16 + lr] = __float2bfloat16(e1 * inv);
            }
        }
    }
}

// ---------------------------------------------------------------------------
extern "C" void kernel_launch(void* const* d_in, const int* in_sizes, int n_in,
                              void* d_out, int out_size, void* d_ws, size_t ws_size,
                              hipStream_t stream) {
    const float* x     = (const float*)d_in[0];
    const float* gn_w  = (const float*)d_in[1];
    const float* gn_b  = (const float*)d_in[2];
    const float* qkv_w = (const float*)d_in[3];
    const float* qkv_b = (const float*)d_in[4];
    const float* pr_w  = (const float*)d_in[5];
    const float* pr_b  = (const float*)d_in[6];
    float* out = (float*)d_out;

    char* w = (char*)d_ws;
    __hip_bfloat16* xnT  = (__hip_bfloat16*)w;                         // 16 MiB [b][s][c]
    __hip_bfloat16* qkT  = (__hip_bfloat16*)(w + (16u << 20));         // 32 MiB [b*s][1024] (q|k)
    __hip_bfloat16* vbuf = (__hip_bfloat16*)(w + (48u << 20));         // 16 MiB [b][c][s]
    __hip_bfloat16* P    = (__hip_bfloat16*)(w + (64u << 20));         // 32 MiB [b][sq][sk]
    __hip_bfloat16* aoT  = (__hip_bfloat16*)(w + (96u << 20));         // 16 MiB [b*s][c]
    __hip_bfloat16* wq   = (__hip_bfloat16*)(w + (112u << 20));        // 1.5 MiB
    __hip_bfloat16* wp   = (__hip_bfloat16*)(w + (114u << 20));        // 0.5 MiB
    float*          stats= (float*)(w + (115u << 20));                 // 4 KiB

    // 1) GroupNorm stats + transposed normalize
    gn_stats_kernel<<<B_ * NGRP, 256, 0, stream>>>(x, stats);
    gn_norm_t_kernel<<<dim3(S_ / 64, C_ / 64, B_), 256, 0, stream>>>(x, gn_w, gn_b, stats, xnT);

    // 2) weight converts
    f2bf_kernel<<<(1536 * 512) / 256, 256, 0, stream>>>(qkv_w, wq, 1536 * 512);
    f2bf_kernel<<<(512 * 512) / 256, 256, 0, stream>>>(pr_w, wp, 512 * 512);

    // 3) q,k GEMM: M = B*S = 16384, N = 1024, K = 512 -> qkT[(b,s)][o]
    mfma_gemm<2, true, false><<<dim3(1024 / 128, 16384 / 128, 1), 256, 0, stream>>>(
        (const unsigned short*)xnT, (const unsigned short*)wq, qkv_b, nullptr, qkT,
        512, 512, 1024, 512, 0, 0, 0, 0, 1.f);

    // 4) v GEMM (batched): M = 512 (c), N = 1024 (s), K = 512 -> v[b][c][s]
    mfma_gemm<1, true, false><<<dim3(1024 / 128, 512 / 128, B_), 256, 0, stream>>>(
        (const unsigned short*)wq + 1024 * 512, (const unsigned short*)xnT,
        qkv_b + 1024, nullptr, vbuf,
        512, 512, 1024, 512, 0, (size_t)S_ * C_, (size_t)512 * S_, 0, 1.f);

    // 5) scores + fused 32-chunk softmax -> P (bf16)
    scores_softmax_kernel<<<dim3(8, 8, B_), 256, 0, stream>>>(
        (const unsigned short*)qkT, (const unsigned short*)qkT + 512, P,
        1024, 1024, 512, (size_t)S_ * 1024, (size_t)S_ * 1024, (size_t)S_ * S_);

    // 6) PV (batched): M = 1024 (sq), N = 512 (c), K = 1024 -> aoT[(b,s)][c]
    mfma_gemm<0, true, false><<<dim3(512 / 128, 1024 / 128, B_), 256, 0, stream>>>(
        (const unsigned short*)P, (const unsigned short*)vbuf, nullptr, nullptr, aoT,
        1024, 1024, 512, 1024, (size_t)S_ * S_, (size_t)512 * S_, (size_t)S_ * 512, 0, 1.f);

    // 7) proj + residual (batched): M = 512 (c), N = 1024 (s), K = 512
    mfma_gemm<1, false, true><<<dim3(1024 / 128, 512 / 128, B_), 256, 0, stream>>>(
        (const unsigned short*)wp, (const unsigned short*)aoT, pr_b, x, out,
        512, 512, 1024, 512, 0, (size_t)S_ * 512, (size_t)C_ * S_, (size_t)C_ * S_, 1.f);
}

// Round 4
// 244.696 us; speedup vs baseline: 5.4367x; 1.0896x over previous
//
#include <hip/hip_runtime.h>
#include <hip/hip_bf16.h>

#define B_    16
#define C_    512
#define S_    1024      // H*W
#define NGRP  32
#define CPG   16

typedef __attribute__((ext_vector_type(8))) short  short8;
typedef __attribute__((ext_vector_type(4))) short  short4v;
typedef __attribute__((ext_vector_type(4))) float  floatx4;

__device__ __forceinline__ unsigned short f2bf(float f) {
    __hip_bfloat16 h = __float2bfloat16(f);
    unsigned short u;
    __builtin_memcpy(&u, &h, 2);
    return u;
}

// ---------------------------------------------------------------------------
// Fused GroupNorm (+transpose to xnT[b][s][c] bf16), single pass over x.
// One block per (batch,group). Thread t holds, for r=0..15, float4 at
// flat = r*1024 + 4t  ->  c = r, s = 4t..4t+3: a complete 4s x 16c register
// sub-tile. No LDS, no second read.
// ---------------------------------------------------------------------------
__global__ __launch_bounds__(256)
void gn_fused_kernel(const float* __restrict__ x, const float* __restrict__ w,
                     const float* __restrict__ bias, __hip_bfloat16* __restrict__ xnT) {
    int bg = blockIdx.x;
    int b = bg >> 5, g = bg & 31;
    const float4* xp = (const float4*)(x + (size_t)bg * (CPG * S_));
    int tid = threadIdx.x;

    float4 vv[16];
    float s = 0.f, ss = 0.f;
#pragma unroll
    for (int r = 0; r < 16; ++r) {
        float4 v = xp[r * 256 + tid];
        vv[r] = v;
        s  += v.x + v.y + v.z + v.w;
        ss += v.x*v.x + v.y*v.y + v.z*v.z + v.w*v.w;
    }
    for (int off = 32; off > 0; off >>= 1) {
        s  += __shfl_down(s, off);
        ss += __shfl_down(ss, off);
    }
    __shared__ float red[2][4];
    __shared__ float msh[2];
    int wid = tid >> 6, lane = tid & 63;
    if (lane == 0) { red[0][wid] = s; red[1][wid] = ss; }
    __syncthreads();
    if (tid == 0) {
        float a = 0.f, c = 0.f;
        for (int i = 0; i < 4; ++i) { a += red[0][i]; c += red[1][i]; }
        float mean = a / (float)(CPG * S_);
        float var  = c / (float)(CPG * S_) - mean * mean;
        msh[0] = mean;
        msh[1] = rsqrtf(var + 1e-5f);
    }
    __syncthreads();
    float mean = msh[0], inv = msh[1];

    float sc[16], sh[16];
#pragma unroll
    for (int c = 0; c < 16; ++c) {
        float wc = w[g * 16 + c];
        sc[c] = inv * wc;
        sh[c] = bias[g * 16 + c] - mean * inv * wc;
    }

    // emit rows s = 4t..4t+3, each 16 bf16 (two 16B stores)
#pragma unroll
    for (int kk = 0; kk < 4; ++kk) {
        unsigned short outp[16];
#pragma unroll
        for (int c = 0; c < 16; ++c) {
            float v = (kk == 0) ? vv[c].x : (kk == 1) ? vv[c].y : (kk == 2) ? vv[c].z : vv[c].w;
            outp[c] = f2bf(v * sc[c] + sh[c]);
        }
        int srow = 4 * tid + kk;
        unsigned short* dst = (unsigned short*)xnT + ((size_t)(b * S_ + srow) * C_ + g * 16);
        *(short8*)dst       = *(short8*)outp;
        *(short8*)(dst + 8) = *(short8*)(outp + 8);
    }
}

// ---------------------------------------------------------------------------
// Vectorized fp32 -> bf16 convert (n multiple of 1024)
// ---------------------------------------------------------------------------
__global__ __launch_bounds__(256)
void f2bf4_kernel(const float* __restrict__ in, unsigned short* __restrict__ out, int n) {
    int i = (blockIdx.x * 256 + threadIdx.x) * 4;
    if (i < n) {
        float4 v = *(const float4*)(in + i);
        short4v o;
        o[0] = (short)f2bf(v.x); o[1] = (short)f2bf(v.y);
        o[2] = (short)f2bf(v.z); o[3] = (short)f2bf(v.w);
        *(short4v*)(out + i) = o;
    }
}

// ---------------------------------------------------------------------------
// Uniform NT bf16 MFMA GEMM: C[m][n] = alpha * sum_k A[m][k]*B[n][k] (+bias)(+resid)
// 128x128x32 tile, 256 threads = 4 waves. BIAS_MODE: 0 none, 1 bias[m], 2 bias[n].
// SWIZ: 1-D grid, XCD-aware decode (batch = lin&7 [+8]), ntsh/nxsh = log2 tiles.
// ---------------------------------------------------------------------------
template<int BIAS_MODE, bool OUT_BF16, bool RESID, bool SWIZ>
__global__ __launch_bounds__(256)
void mfma_gemm(const unsigned short* __restrict__ A, const unsigned short* __restrict__ Bm,
               const float* __restrict__ bias, const float* __restrict__ resid,
               void* __restrict__ Yv,
               int lda, int ldb, int ldy, int K,
               size_t sA, size_t sB, size_t sY, size_t sR, float alpha,
               int ntsh, int nxsh)
{
    __shared__ unsigned short As[128 * 32];
    __shared__ unsigned short Bs[128 * 32];
    int bx, by, bz;
    if (SWIZ) {
        int lin = blockIdx.x;
        int xcd = lin & 7, sup = lin >> 3;
        bz = xcd + ((sup >> ntsh) << 3);
        int tile = sup & ((1 << ntsh) - 1);
        bx = tile & ((1 << nxsh) - 1);
        by = tile >> nxsh;
    } else { bx = blockIdx.x; by = blockIdx.y; bz = blockIdx.z; }

    const unsigned short* Ab = A  + (size_t)bz * sA;
    const unsigned short* Bb = Bm + (size_t)bz * sB;
    const int tid = threadIdx.x, wave = tid >> 6, lane = tid & 63;
    const int m0 = by * 128, n0 = bx * 128;
    const int wr = wave >> 1, wc = wave & 1, lr = lane & 15, kq = lane >> 4;
    const int row0 = tid >> 2, kc0 = (tid & 3) << 3;

    floatx4 acc[4][4] = {};

    for (int k0 = 0; k0 < K; k0 += 32) {
        __syncthreads();
#pragma unroll
        for (int r = 0; r < 2; ++r) {
            const unsigned short* ga = Ab + (size_t)(m0 + r * 64 + row0) * lda + k0 + kc0;
            __builtin_amdgcn_global_load_lds(
                (const __attribute__((address_space(1))) void*)ga,
                (__attribute__((address_space(3))) void*)(As + (r * 256 + wave * 64) * 8),
                16, 0, 0);
            const unsigned short* gb = Bb + (size_t)(n0 + r * 64 + row0) * ldb + k0 + kc0;
            __builtin_amdgcn_global_load_lds(
                (const __attribute__((address_space(1))) void*)gb,
                (__attribute__((address_space(3))) void*)(Bs + (r * 256 + wave * 64) * 8),
                16, 0, 0);
        }
        __syncthreads();

        short8 af[4], bfr[4];
#pragma unroll
        for (int i = 0; i < 4; ++i)
            af[i] = *(const short8*)&As[(wr * 64 + i * 16 + lr) * 32 + kq * 8];
#pragma unroll
        for (int j = 0; j < 4; ++j)
            bfr[j] = *(const short8*)&Bs[(wc * 64 + j * 16 + lr) * 32 + kq * 8];
#pragma unroll
        for (int i = 0; i < 4; ++i)
#pragma unroll
            for (int j = 0; j < 4; ++j)
                acc[i][j] = __builtin_amdgcn_mfma_f32_16x16x32_bf16(af[i], bfr[j], acc[i][j], 0, 0, 0);
    }

    const size_t ybase = (size_t)bz * sY;
    const size_t rbase = (size_t)bz * sR;
#pragma unroll
    for (int i = 0; i < 4; ++i) {
#pragma unroll
        for (int r = 0; r < 4; ++r) {
            int m = m0 + wr * 64 + i * 16 + kq * 4 + r;
            float bm = (BIAS_MODE == 1) ? bias[m] : 0.f;
#pragma unroll
            for (int j = 0; j < 4; ++j) {
                int n = n0 + wc * 64 + j * 16 + lr;
                float vv = acc[i][j][r] * alpha + bm;
                if (BIAS_MODE == 2) vv += bias[n];
                if (RESID) vv += resid[rbase + (size_t)m * ldy + n];
                if (OUT_BF16)
                    ((__hip_bfloat16*)Yv)[ybase + (size_t)m * ldy + n] = __float2bfloat16(vv);
                else
                    ((float*)Yv)[ybase + (size_t)m * ldy + n] = vv;
            }
        }
    }
}

// ---------------------------------------------------------------------------
// Scores^T GEMM + fused 32-key-chunk softmax + LDS transpose.
// Computes S^T[key][sq] = sum_c k[key][c] q[sq][c]; keys are ROWS, so a 32-key
// chunk is 8 in-lane values (i-pair x 4 regs) + reduce over lane>>4 (2 shfl).
// P written in [sq][key] layout via padded-LDS transpose, dwordx4 stores.
// XCD-swizzled 1-D grid (1024 blocks, ntiles=64, nx=8).
// ---------------------------------------------------------------------------
__global__ __launch_bounds__(256)
void scores_softmax_kernel(const unsigned short* __restrict__ A,   // k-half
                           const unsigned short* __restrict__ Bm,  // q-half
                           unsigned short* __restrict__ P)
{
    __shared__ unsigned short smem[128 * 136];   // 34816 B; reused: AsBs then P-tile
    unsigned short* As = smem;                    // 128*32
    unsigned short* Bs = smem + 128 * 32;         // 128*32

    int lin = blockIdx.x;
    int xcd = lin & 7, sup = lin >> 3;
    int bz = xcd + ((sup >> 6) << 3);
    int tile = sup & 63;
    int bx = tile & 7, by = tile >> 3;

    const size_t sAB = (size_t)S_ * 1024;
    const unsigned short* Ab = A  + (size_t)bz * sAB;
    const unsigned short* Bb = Bm + (size_t)bz * sAB;
    const int tid = threadIdx.x, wave = tid >> 6, lane = tid & 63;
    const int m0 = by * 128, n0 = bx * 128;     // m = key, n = sq
    const int wr = wave >> 1, wc = wave & 1, lr = lane & 15, kq = lane >> 4;
    const int row0 = tid >> 2, kc0 = (tid & 3) << 3;

    floatx4 acc[4][4] = {};

    for (int k0 = 0; k0 < 512; k0 += 32) {
        __syncthreads();
#pragma unroll
        for (int r = 0; r < 2; ++r) {
            const unsigned short* ga = Ab + (size_t)(m0 + r * 64 + row0) * 1024 + k0 + kc0;
            __builtin_amdgcn_global_load_lds(
                (const __attribute__((address_space(1))) void*)ga,
                (__attribute__((address_space(3))) void*)(As + (r * 256 + wave * 64) * 8),
                16, 0, 0);
            const unsigned short* gb = Bb + (size_t)(n0 + r * 64 + row0) * 1024 + k0 + kc0;
            __builtin_amdgcn_global_load_lds(
                (const __attribute__((address_space(1))) void*)gb,
                (__attribute__((address_space(3))) void*)(Bs + (r * 256 + wave * 64) * 8),
                16, 0, 0);
        }
        __syncthreads();

        short8 af[4], bfr[4];
#pragma unroll
        for (int i = 0; i < 4; ++i)
            af[i] = *(const short8*)&As[(wr * 64 + i * 16 + lr) * 32 + kq * 8];
#pragma unroll
        for (int j = 0; j < 4; ++j)
            bfr[j] = *(const short8*)&Bs[(wc * 64 + j * 16 + lr) * 32 + kq * 8];
#pragma unroll
        for (int i = 0; i < 4; ++i)
#pragma unroll
            for (int j = 0; j < 4; ++j)
                acc[i][j] = __builtin_amdgcn_mfma_f32_16x16x32_bf16(af[i], bfr[j], acc[i][j], 0, 0, 0);
    }

    __syncthreads();   // main loop done: safe to reuse smem as the P-tile

    // softmax per (sq-frag j, chunk h); chunk = keys [wr*64 + 32h, +32)
#pragma unroll
    for (int j = 0; j < 4; ++j) {
        int sq_l = wc * 64 + j * 16 + lr;
#pragma unroll
        for (int h = 0; h < 2; ++h) {
            float v0[4], v1[4];
            float mx = -1e30f;
#pragma unroll
            for (int r = 0; r < 4; ++r) {
                v0[r] = acc[2 * h][j][r]     * 0.125f;
                v1[r] = acc[2 * h + 1][j][r] * 0.125f;
                mx = fmaxf(mx, fmaxf(v0[r], v1[r]));
            }
            mx = fmaxf(mx, __shfl_xor(mx, 16));
            mx = fmaxf(mx, __shfl_xor(mx, 32));
            float sm = 0.f;
#pragma unroll
            for (int r = 0; r < 4; ++r) {
                v0[r] = __expf(v0[r] - mx);
                v1[r] = __expf(v1[r] - mx);
                sm += v0[r] + v1[r];
            }
            sm += __shfl_xor(sm, 16);
            sm += __shfl_xor(sm, 32);
            float inv = 1.f / sm;
            short4v p0, p1;
#pragma unroll
            for (int r = 0; r < 4; ++r) {
                p0[r] = (short)f2bf(v0[r] * inv);
                p1[r] = (short)f2bf(v1[r] * inv);
            }
            int key0 = wr * 64 + 32 * h + kq * 4;
            *(short4v*)&smem[sq_l * 136 + key0]      = p0;
            *(short4v*)&smem[sq_l * 136 + key0 + 16] = p1;
        }
    }
    __syncthreads();

    // read back transposed tile, vector-store to P[sq][key]
    int row = tid >> 1, half = tid & 1;
    const unsigned short* src = smem + row * 136 + half * 64;
    size_t gbase = (size_t)bz * ((size_t)S_ * S_) + (size_t)(n0 + row) * 1024 + m0 + half * 64;
#pragma unroll
    for (int t = 0; t < 8; ++t) {
        short8 v = *(const short8*)(src + t * 8);
        *(short8*)(P + gbase + t * 8) = v;
    }
}

// ---------------------------------------------------------------------------
extern "C" void kernel_launch(void* const* d_in, const int* in_sizes, int n_in,
                              void* d_out, int out_size, void* d_ws, size_t ws_size,
                              hipStream_t stream) {
    const float* x     = (const float*)d_in[0];
    const float* gn_w  = (const float*)d_in[1];
    const float* gn_b  = (const float*)d_in[2];
    const float* qkv_w = (const float*)d_in[3];
    const float* qkv_b = (const float*)d_in[4];
    const float* pr_w  = (const float*)d_in[5];
    const float* pr_b  = (const float*)d_in[6];
    float* out = (float*)d_out;

    char* w = (char*)d_ws;
    __hip_bfloat16* xnT  = (__hip_bfloat16*)w;                         // 16 MiB [b][s][c]
    __hip_bfloat16* qkT  = (__hip_bfloat16*)(w + (16u << 20));         // 32 MiB [b*s][1024] (q|k)
    __hip_bfloat16* vbuf = (__hip_bfloat16*)(w + (48u << 20));         // 16 MiB [b][c][s]
    __hip_bfloat16* P    = (__hip_bfloat16*)(w + (64u << 20));         // 32 MiB [b][sq][sk]
    __hip_bfloat16* aoT  = (__hip_bfloat16*)(w + (96u << 20));         // 16 MiB [b*s][c]
    __hip_bfloat16* wq   = (__hip_bfloat16*)(w + (112u << 20));        // 1.5 MiB
    __hip_bfloat16* wp   = (__hip_bfloat16*)(w + (114u << 20));        // 0.5 MiB

    // 1) fused GroupNorm -> xnT (bf16, [b][s][c])
    gn_fused_kernel<<<B_ * NGRP, 256, 0, stream>>>(x, gn_w, gn_b, xnT);

    // 2) weight converts (vectorized)
    f2bf4_kernel<<<(1536 * 512) / 1024, 256, 0, stream>>>(qkv_w, (unsigned short*)wq, 1536 * 512);
    f2bf4_kernel<<<(512 * 512) / 1024, 256, 0, stream>>>(pr_w, (unsigned short*)wp, 512 * 512);

    // 3) q,k GEMM: M = B*S = 16384, N = 1024, K = 512 -> qkT[(b,s)][o]
    mfma_gemm<2, true, false, false><<<dim3(1024 / 128, 16384 / 128, 1), 256, 0, stream>>>(
        (const unsigned short*)xnT, (const unsigned short*)wq, qkv_b, nullptr, qkT,
        512, 512, 1024, 512, 0, 0, 0, 0, 1.f, 0, 0);

    // 4) v GEMM (batched): M = 512 (c), N = 1024 (s), K = 512 -> v[b][c][s]
    mfma_gemm<1, true, false, false><<<dim3(1024 / 128, 512 / 128, B_), 256, 0, stream>>>(
        (const unsigned short*)wq + 1024 * 512, (const unsigned short*)xnT,
        qkv_b + 1024, nullptr, vbuf,
        512, 512, 1024, 512, 0, (size_t)S_ * C_, (size_t)512 * S_, 0, 1.f, 0, 0);

    // 5) scores^T + fused softmax + transpose -> P[sq][key] (bf16), XCD-swizzled
    scores_softmax_kernel<<<1024, 256, 0, stream>>>(
        (const unsigned short*)qkT + 512, (const unsigned short*)qkT, (unsigned short*)P);

    // 6) PV (batched, XCD-swizzled): M = 1024 (sq), N = 512 (c), K = 1024 -> aoT[(b,s)][c]
    mfma_gemm<0, true, false, true><<<512, 256, 0, stream>>>(
        (const unsigned short*)P, (const unsigned short*)vbuf, nullptr, nullptr, aoT,
        1024, 1024, 512, 1024, (size_t)S_ * S_, (size_t)512 * S_, (size_t)S_ * 512, 0, 1.f,
        5, 2);

    // 7) proj + residual (batched): M = 512 (c), N = 1024 (s), K = 512
    mfma_gemm<1, false, true, false><<<dim3(1024 / 128, 512 / 128, B_), 256, 0, stream>>>(
        (const unsigned short*)wp, (const unsigned short*)aoT, pr_b, x, out,
        512, 512, 1024, 512, 0, (size_t)S_ * 512, (size_t)C_ * S_, (size_t)C_ * S_, 1.f, 0, 0);
}